// Round 3
// baseline (2309.014 us; speedup 1.0000x reference)
//
#include <hip/hip_runtime.h>

// out[b,n,f] = sum_{l,m} x1[b,l,f] * x2[b,m,f] * cg[l,m,n]
// B=50000, d1=d2=9, d3=25, MUL=512, fp32.
//
// R2 lesson: float2/thread version (VGPR=100) ran at 23% occupancy,
// latency-stalled on cg s_load waits + global latency; 1512 us vs ~600 us
// floor. This version: ONE f per thread, 512-thread block per b ->
// ~43 data VGPRs, capped at 64 via launch_bounds -> 8 waves/SIMD.
// Non-temporal loads/stores: x1/x2/out are streamed exactly once.
// All loops have literal constant bounds (R1 lesson: SROA needs full unroll).

#define BATCH 50000
#define D1 9
#define D2 9
#define D3 25
#define MUL 512

__global__ void __launch_bounds__(512, 8) tp_kernel(
    const float* __restrict__ x1,
    const float* __restrict__ x2,
    const float* __restrict__ cg,
    float* __restrict__ out) {

    const int b = blockIdx.x;
    const int f = threadIdx.x;  // one f-channel per thread

    const float* x1p = x1 + (size_t)b * (D1 * MUL) + f;
    const float* x2p = x2 + (size_t)b * (D2 * MUL) + f;
    float*       op  = out + (size_t)b * (D3 * MUL) + f;

    float a[D1], c[D2], acc[D3];

    #pragma unroll
    for (int l = 0; l < D1; ++l) a[l] = __builtin_nontemporal_load(x1p + l * MUL);
    #pragma unroll
    for (int m = 0; m < D2; ++m) c[m] = __builtin_nontemporal_load(x2p + m * MUL);
    #pragma unroll
    for (int n = 0; n < D3; ++n) acc[n] = 0.0f;

    #pragma unroll
    for (int L = 0; L < D1; ++L) {
        #pragma unroll
        for (int M = 0; M < D2; ++M) {
            const float p = a[L] * c[M];
            #pragma unroll
            for (int N = 0; N < D3; ++N) {
                // constant-foldable after full unroll:
                const int l1 = (L >= 4) ? 2 : (L >= 1) ? 1 : 0;
                const int l2 = (M >= 4) ? 2 : (M >= 1) ? 1 : 0;
                const int l3 = (N >= 16) ? 4 : (N >= 9) ? 3 : (N >= 4) ? 2 : (N >= 1) ? 1 : 0;
                const int lo = (l1 > l2) ? (l1 - l2) : (l2 - l1);
                if (l3 >= lo && l3 <= l1 + l2) {
                    const float w = cg[(L * D2 + M) * D3 + N];  // uniform -> s_load
                    acc[N] = fmaf(p, w, acc[N]);
                }
            }
        }
    }

    #pragma unroll
    for (int n = 0; n < D3; ++n)
        __builtin_nontemporal_store(acc[n], op + n * MUL);
}

extern "C" void kernel_launch(void* const* d_in, const int* in_sizes, int n_in,
                              void* d_out, int out_size, void* d_ws, size_t ws_size,
                              hipStream_t stream) {
    const float* x1 = (const float*)d_in[0];
    const float* x2 = (const float*)d_in[1];
    const float* cg = (const float*)d_in[2];
    float* out = (float*)d_out;

    dim3 grid(BATCH);
    dim3 block(512);
    tp_kernel<<<grid, block, 0, stream>>>(x1, x2, cg, out);
}

// Round 4
// 1835.285 us; speedup vs baseline: 1.2581x; 1.2581x over previous
//
#include <hip/hip_runtime.h>

// out[b,n,f] = sum_{l,m} x1[b,l,f] * x2[b,m,f] * cg[l,m,n]
// B=50000, d1=d2=9, d3=25, MUL=512, fp32.
//
// R1 lesson: literal constant loop bounds -> full unroll -> SROA keeps
//   a[]/c[]/acc[] in VGPRs (variable bounds => 166 GB spill traffic).
// R3 lesson: __launch_bounds__(512,8) squeezed VGPR to 32 -> compiler
//   restructured into reloads/recompute -> 5x VALU instruction bloat
//   (VALUBusy 97%, 2309 us). Natural allocation (~56-64 VGPR) already
//   allows 7-8 waves/SIMD; do NOT over-constrain the allocator.
//
// This version: 1 f-channel per thread, 256-thread blocks, 2 blocks per
// batch row (grid 100000). Plain __launch_bounds__(256), NT streams.

#define BATCH 50000
#define D1 9
#define D2 9
#define D3 25
#define MUL 512

__global__ void __launch_bounds__(256) tp_kernel(
    const float* __restrict__ x1,
    const float* __restrict__ x2,
    const float* __restrict__ cg,
    float* __restrict__ out) {

    const int b = blockIdx.x >> 1;                       // batch row
    const int f = ((blockIdx.x & 1) << 8) + threadIdx.x; // f-channel 0..511

    const float* x1p = x1 + (size_t)b * (D1 * MUL) + f;
    const float* x2p = x2 + (size_t)b * (D2 * MUL) + f;
    float*       op  = out + (size_t)b * (D3 * MUL) + f;

    float a[D1], c[D2], acc[D3];

    #pragma unroll
    for (int l = 0; l < D1; ++l) a[l] = __builtin_nontemporal_load(x1p + l * MUL);
    #pragma unroll
    for (int m = 0; m < D2; ++m) c[m] = __builtin_nontemporal_load(x2p + m * MUL);
    #pragma unroll
    for (int n = 0; n < D3; ++n) acc[n] = 0.0f;

    #pragma unroll
    for (int L = 0; L < D1; ++L) {
        #pragma unroll
        for (int M = 0; M < D2; ++M) {
            const float p = a[L] * c[M];
            #pragma unroll
            for (int N = 0; N < D3; ++N) {
                // constant-foldable after full unroll:
                const int l1 = (L >= 4) ? 2 : (L >= 1) ? 1 : 0;
                const int l2 = (M >= 4) ? 2 : (M >= 1) ? 1 : 0;
                const int l3 = (N >= 16) ? 4 : (N >= 9) ? 3 : (N >= 4) ? 2 : (N >= 1) ? 1 : 0;
                const int lo = (l1 > l2) ? (l1 - l2) : (l2 - l1);
                if (l3 >= lo && l3 <= l1 + l2) {
                    const float w = cg[(L * D2 + M) * D3 + N];  // uniform -> s_load
                    acc[N] = fmaf(p, w, acc[N]);
                }
            }
        }
    }

    #pragma unroll
    for (int n = 0; n < D3; ++n)
        __builtin_nontemporal_store(acc[n], op + n * MUL);
}

extern "C" void kernel_launch(void* const* d_in, const int* in_sizes, int n_in,
                              void* d_out, int out_size, void* d_ws, size_t ws_size,
                              hipStream_t stream) {
    const float* x1 = (const float*)d_in[0];
    const float* x2 = (const float*)d_in[1];
    const float* cg = (const float*)d_in[2];
    float* out = (float*)d_out;

    dim3 grid(BATCH * 2);
    dim3 block(256);
    tp_kernel<<<grid, block, 0, stream>>>(x1, x2, cg, out);
}

// Round 5
// 1779.975 us; speedup vs baseline: 1.2972x; 1.0311x over previous
//
#include <hip/hip_runtime.h>

// out[b,n,f] = sum_{l,m} x1[b,l,f] * x2[b,m,f] * cg[l,m,n]
// B=50000, d1=d2=9, d3=25, MUL=512, fp32.
//
// R1 lesson: literal constant loop bounds -> full unroll -> SROA keeps
//   arrays in VGPRs (variable bounds => 166 GB spill traffic).
// R3/R4 lesson: with 1 float/thread the allocator CHOOSES a 32-VGPR
//   schedule (acc[25]+temps) and re-loads a[]/c[] per use -> 5x VALU
//   instruction bloat (VALUBusy ~96%, >2 ms). launch_bounds didn't cause
//   it and didn't fix it.
// R5: pin the 18 loaded values into VGPRs with empty asm ("+v") so the
//   compiler cannot sink/rematerialize the loads; forces the lean ~60-VGPR
//   straight-line FMA nest (8 waves/SIMD still fine).

#define BATCH 50000
#define D1 9
#define D2 9
#define D3 25
#define MUL 512

__global__ void __launch_bounds__(256) tp_kernel(
    const float* __restrict__ x1,
    const float* __restrict__ x2,
    const float* __restrict__ cg,
    float* __restrict__ out) {

    const int b = blockIdx.x >> 1;                       // batch row
    const int f = ((blockIdx.x & 1) << 8) + threadIdx.x; // f-channel 0..511

    const float* x1p = x1 + (size_t)b * (D1 * MUL) + f;
    const float* x2p = x2 + (size_t)b * (D2 * MUL) + f;
    float*       op  = out + (size_t)b * (D3 * MUL) + f;

    float a[D1], c[D2], acc[D3];

    #pragma unroll
    for (int l = 0; l < D1; ++l) a[l] = x1p[l * MUL];
    #pragma unroll
    for (int m = 0; m < D2; ++m) c[m] = x2p[m * MUL];

    // Pin loaded values to VGPRs: forbids re-load/remat scheduling (R4 bug).
    #pragma unroll
    for (int l = 0; l < D1; ++l) asm volatile("" : "+v"(a[l]));
    #pragma unroll
    for (int m = 0; m < D2; ++m) asm volatile("" : "+v"(c[m]));

    #pragma unroll
    for (int n = 0; n < D3; ++n) acc[n] = 0.0f;

    #pragma unroll
    for (int L = 0; L < D1; ++L) {
        #pragma unroll
        for (int M = 0; M < D2; ++M) {
            const float p = a[L] * c[M];
            #pragma unroll
            for (int N = 0; N < D3; ++N) {
                // constant-foldable after full unroll:
                const int l1 = (L >= 4) ? 2 : (L >= 1) ? 1 : 0;
                const int l2 = (M >= 4) ? 2 : (M >= 1) ? 1 : 0;
                const int l3 = (N >= 16) ? 4 : (N >= 9) ? 3 : (N >= 4) ? 2 : (N >= 1) ? 1 : 0;
                const int lo = (l1 > l2) ? (l1 - l2) : (l2 - l1);
                if (l3 >= lo && l3 <= l1 + l2) {
                    const float w = cg[(L * D2 + M) * D3 + N];  // uniform -> s_load
                    acc[N] = fmaf(p, w, acc[N]);
                }
            }
        }
    }

    #pragma unroll
    for (int n = 0; n < D3; ++n)
        __builtin_nontemporal_store(acc[n], op + n * MUL);
}

extern "C" void kernel_launch(void* const* d_in, const int* in_sizes, int n_in,
                              void* d_out, int out_size, void* d_ws, size_t ws_size,
                              hipStream_t stream) {
    const float* x1 = (const float*)d_in[0];
    const float* x2 = (const float*)d_in[1];
    const float* cg = (const float*)d_in[2];
    float* out = (float*)d_out;

    dim3 grid(BATCH * 2);
    dim3 block(256);
    tp_kernel<<<grid, block, 0, stream>>>(x1, x2, cg, out);
}

// Round 6
// 1098.241 us; speedup vs baseline: 2.1025x; 1.6208x over previous
//
#include <hip/hip_runtime.h>

// out[b,n,f] = sum_{l,m} x1[b,l,f] * x2[b,m,f] * cg[l,m,n]
// B=50000, d1=d2=9, d3=25, MUL=512, fp32 in/out.
//
// R2-R5 lesson: pure-VALU scalar path executes ~3-4.5x the source FMA count
// (backend chooses 32-arch-VGPR schedules, remat/moves) -> stuck ~1.5-2 ms.
// This version moves the contraction onto matrix cores:
//   per b:  out[n,f] = sum_k W[k,n] * S[k,f],  k=(l,m) in [0,81) pad 96,
//           S[k,f] = x1[l,f]*x2[m,f]  (81 muls/channel, bf16, LDS),
//           W[k,n] = cg[l,m,n]        (bf16, per-lane regs, L1-resident)
// via mfma_f32_16x16x32_bf16 (fp32 accumulate). M=32 (n pad), K=96, N=512.
// Block: 256 thr / 4 waves / 256 f (2 blocks per b). LDS S: 256 rows x 208 B
// (pitch 13*16B, odd -> conflict-free b128). MFMA+VALU ~200 us chip-wide,
// memory floor ~600 us -> memory-bound.

#define BATCH 50000
#define MUL   512
#define D3    25
#define FCHUNK 256
#define ROWB  208   // 104 bf16: 96 K-values + 8 pad

typedef __bf16 bf16x8 __attribute__((ext_vector_type(8)));
typedef float  f32x4  __attribute__((ext_vector_type(4)));

__device__ inline unsigned pack2(float lo, float hi) {
    unsigned short l = __builtin_bit_cast(unsigned short, (__bf16)lo);
    unsigned short h = __builtin_bit_cast(unsigned short, (__bf16)hi);
    return (unsigned)l | ((unsigned)h << 16);
}

__global__ void __launch_bounds__(256) tp_kernel(
    const float* __restrict__ x1,
    const float* __restrict__ x2,
    const float* __restrict__ cg,
    float* __restrict__ out) {

    extern __shared__ char smem[];

    const int b     = blockIdx.x >> 1;
    const int chunk = blockIdx.x & 1;
    const int tid   = threadIdx.x;
    const int lane  = tid & 63;
    const int wv    = tid >> 6;

    // ---- phase 0: x-loads (coalesced) + A-fragments (W from cg, L1-hot) ----
    const size_t xbase = (size_t)b * (9 * MUL) + chunk * FCHUNK + tid;
    float a[9], c[9];
    #pragma unroll
    for (int l = 0; l < 9; ++l) a[l] = x1[xbase + l * MUL];
    #pragma unroll
    for (int m = 0; m < 9; ++m) c[m] = x2[xbase + m * MUL];

    // A[mt][ks]: row n = 16*mt + (lane&15), k = 32*ks + 8*(lane>>4) + j
    bf16x8 afrag[2][3];
    #pragma unroll
    for (int mt = 0; mt < 2; ++mt) {
        const int n = 16 * mt + (lane & 15);
        #pragma unroll
        for (int ks = 0; ks < 3; ++ks) {
            #pragma unroll
            for (int j = 0; j < 8; ++j) {
                const int k = 32 * ks + 8 * (lane >> 4) + j;
                float w = (k < 81 && n < 25) ? cg[k * 25 + n] : 0.0f;
                afrag[mt][ks][j] = (__bf16)w;
            }
        }
    }

    // ---- phase 1: S[k,f] products -> bf16 -> LDS (row f, 96 k + pad) ----
    uint4* row = reinterpret_cast<uint4*>(smem + tid * ROWB);
    #pragma unroll
    for (int ch = 0; ch < 12; ++ch) {
        unsigned t0, t1, t2, t3;
        {
            const int k0 = ch * 8;
            float p0 = (k0+0 < 81) ? a[(k0+0)/9] * c[(k0+0)%9] : 0.0f;
            float p1 = (k0+1 < 81) ? a[(k0+1)/9] * c[(k0+1)%9] : 0.0f;
            float p2 = (k0+2 < 81) ? a[(k0+2)/9] * c[(k0+2)%9] : 0.0f;
            float p3 = (k0+3 < 81) ? a[(k0+3)/9] * c[(k0+3)%9] : 0.0f;
            float p4 = (k0+4 < 81) ? a[(k0+4)/9] * c[(k0+4)%9] : 0.0f;
            float p5 = (k0+5 < 81) ? a[(k0+5)/9] * c[(k0+5)%9] : 0.0f;
            float p6 = (k0+6 < 81) ? a[(k0+6)/9] * c[(k0+6)%9] : 0.0f;
            float p7 = (k0+7 < 81) ? a[(k0+7)/9] * c[(k0+7)%9] : 0.0f;
            t0 = pack2(p0, p1); t1 = pack2(p2, p3);
            t2 = pack2(p4, p5); t3 = pack2(p6, p7);
        }
        row[ch] = make_uint4(t0, t1, t2, t3);
    }

    __syncthreads();

    // ---- phase 2: MFMA. wave wv owns local f in [64*wv, 64*wv+64) ----
    f32x4 acc[2][4];
    #pragma unroll
    for (int mt = 0; mt < 2; ++mt)
        #pragma unroll
        for (int ft = 0; ft < 4; ++ft)
            acc[mt][ft] = (f32x4){0.f, 0.f, 0.f, 0.f};

    #pragma unroll
    for (int ft = 0; ft < 4; ++ft) {
        const char* bbase = smem + (wv * 64 + ft * 16 + (lane & 15)) * ROWB
                                 + (lane >> 4) * 16;
        #pragma unroll
        for (int ks = 0; ks < 3; ++ks) {
            bf16x8 bfrag = *reinterpret_cast<const bf16x8*>(bbase + ks * 64);
            acc[0][ft] = __builtin_amdgcn_mfma_f32_16x16x32_bf16(
                afrag[0][ks], bfrag, acc[0][ft], 0, 0, 0);
            acc[1][ft] = __builtin_amdgcn_mfma_f32_16x16x32_bf16(
                afrag[1][ks], bfrag, acc[1][ft], 0, 0, 0);
        }
    }

    // ---- epilogue: D col = lane&15 (f), row = (lane>>4)*4 + r (n) ----
    const int fg = chunk * FCHUNK + wv * 64 + (lane & 15);
    #pragma unroll
    for (int mt = 0; mt < 2; ++mt) {
        #pragma unroll
        for (int r = 0; r < 4; ++r) {
            const int n = 16 * mt + (lane >> 4) * 4 + r;
            if (n < 25) {
                #pragma unroll
                for (int ft = 0; ft < 4; ++ft) {
                    size_t o = (size_t)b * (D3 * MUL) + (size_t)n * MUL
                             + fg + ft * 16;
                    __builtin_nontemporal_store(acc[mt][ft][r], out + o);
                }
            }
        }
    }
}

extern "C" void kernel_launch(void* const* d_in, const int* in_sizes, int n_in,
                              void* d_out, int out_size, void* d_ws, size_t ws_size,
                              hipStream_t stream) {
    const float* x1 = (const float*)d_in[0];
    const float* x2 = (const float*)d_in[1];
    const float* cg = (const float*)d_in[2];
    float* out = (float*)d_out;

    dim3 grid(BATCH * 2);
    dim3 block(256);
    tp_kernel<<<grid, block, FCHUNK * ROWB, stream>>>(x1, x2, cg, out);
}

// Round 7
// 858.097 us; speedup vs baseline: 2.6909x; 1.2799x over previous
//
#include <hip/hip_runtime.h>

// out[b,n,f] = sum_{l,m} x1[b,l,f] * x2[b,m,f] * cg[l,m,n]
// B=50000, d1=d2=9, d3=25, MUL=512, fp32 in/out.
//
// MFMA formulation (R6, 1098us): per b, out[n,f] = sum_k W[k,n]*S[k,f],
// k=(l,m) in [0,81) pad 96; S=x1*x2 products in LDS bf16; W=cg bf16 in regs;
// mfma_f32_16x16x32_bf16, fp32 accum. absmax 0.5 vs 1.38 threshold.
//
// R7 changes (theory: R6 was serial per-row with afrag redone per block):
//  - RPB=10 batch rows per block -> 48 cg loads + cvts amortized 10x
//  - NO __syncthreads at all: wave wv writes LDS rows [64wv,64wv+64) and
//    reads only those rows (intra-wave; DS ops in-order per wave)
//  - prefetch next row's x into regs after S-pack: 18 global loads hide
//    under current row's ds_read + 24 MFMA + 25 stores
// LDS 256 rows x 208 B (pitch 13*16B -> 2-way worst bank aliasing = free).

#define BATCH 50000
#define MUL   512
#define D3    25
#define FCHUNK 256
#define ROWB  208
#define RPB   10

typedef __bf16 bf16x8 __attribute__((ext_vector_type(8)));
typedef float  f32x4  __attribute__((ext_vector_type(4)));

__global__ void __launch_bounds__(256) tp_kernel(
    const float* __restrict__ x1,
    const float* __restrict__ x2,
    const float* __restrict__ cg,
    float* __restrict__ out) {

    extern __shared__ char smem[];

    const int bg    = blockIdx.x >> 1;   // row-group index
    const int chunk = blockIdx.x & 1;    // which 256 f-channels
    const int tid   = threadIdx.x;
    const int lane  = tid & 63;
    const int wv    = tid >> 6;
    const int b0    = bg * RPB;

    // ---- W fragments once per block (cg 8KB, L2-hot after first blocks) ----
    // A[mt][ks]: row n = 16*mt + (lane&15), k = 32*ks + 8*(lane>>4) + j
    bf16x8 afrag[2][3];
    #pragma unroll
    for (int mt = 0; mt < 2; ++mt) {
        const int n = 16 * mt + (lane & 15);
        #pragma unroll
        for (int ks = 0; ks < 3; ++ks) {
            #pragma unroll
            for (int j = 0; j < 8; ++j) {
                const int k = 32 * ks + 8 * (lane >> 4) + j;
                float w = (k < 81 && n < D3) ? cg[k * D3 + n] : 0.0f;
                afrag[mt][ks][j] = (__bf16)w;
            }
        }
    }

    const int fl = chunk * FCHUNK + tid;               // this thread's channel
    const float* x1p = x1 + (size_t)b0 * (9 * MUL) + fl;
    const float* x2p = x2 + (size_t)b0 * (9 * MUL) + fl;
    const int fg = chunk * FCHUNK + wv * 64 + (lane & 15);
    float* op = out + (size_t)b0 * (D3 * MUL) + fg;

    float a[9], c[9];
    #pragma unroll
    for (int l = 0; l < 9; ++l) a[l] = x1p[l * MUL];
    #pragma unroll
    for (int m = 0; m < 9; ++m) c[m] = x2p[m * MUL];

    uint4* row = reinterpret_cast<uint4*>(smem + tid * ROWB);
    const char* bbase0 = smem + (size_t)(wv * 64 + (lane & 15)) * ROWB
                              + (lane >> 4) * 16;

    for (int r = 0; r < RPB; ++r) {
        // ---- S products -> bf16 -> own LDS row (96 k + 8 pad) ----
        #pragma unroll
        for (int ch = 0; ch < 12; ++ch) {
            bf16x8 v;
            #pragma unroll
            for (int j = 0; j < 8; ++j) {
                const int k = ch * 8 + j;
                const float p = (k < 81) ? a[k / 9] * c[k % 9] : 0.0f;
                v[j] = (__bf16)p;
            }
            row[ch] = __builtin_bit_cast(uint4, v);
        }

        // ---- prefetch next row's x (latency hides under MFMA below) ----
        x1p += 9 * MUL;
        x2p += 9 * MUL;
        if (r != RPB - 1) {
            #pragma unroll
            for (int l = 0; l < 9; ++l) a[l] = x1p[l * MUL];
            #pragma unroll
            for (int m = 0; m < 9; ++m) c[m] = x2p[m * MUL];
        }

        // ---- B fragments from own rows, MFMA ----
        f32x4 acc[2][4];
        #pragma unroll
        for (int mt = 0; mt < 2; ++mt)
            #pragma unroll
            for (int ft = 0; ft < 4; ++ft)
                acc[mt][ft] = (f32x4){0.f, 0.f, 0.f, 0.f};

        #pragma unroll
        for (int ft = 0; ft < 4; ++ft) {
            const char* bb = bbase0 + ft * 16 * ROWB;
            #pragma unroll
            for (int ks = 0; ks < 3; ++ks) {
                bf16x8 bfrag = *reinterpret_cast<const bf16x8*>(bb + ks * 64);
                acc[0][ft] = __builtin_amdgcn_mfma_f32_16x16x32_bf16(
                    afrag[0][ks], bfrag, acc[0][ft], 0, 0, 0);
                acc[1][ft] = __builtin_amdgcn_mfma_f32_16x16x32_bf16(
                    afrag[1][ks], bfrag, acc[1][ft], 0, 0, 0);
            }
        }

        // ---- stores: D col = lane&15 (f), row = (lane>>4)*4 + rr (n) ----
        #pragma unroll
        for (int mt = 0; mt < 2; ++mt) {
            #pragma unroll
            for (int rr = 0; rr < 4; ++rr) {
                const int n = 16 * mt + (lane >> 4) * 4 + rr;
                if (n < D3) {
                    #pragma unroll
                    for (int ft = 0; ft < 4; ++ft)
                        __builtin_nontemporal_store(
                            acc[mt][ft][rr], op + (size_t)n * MUL + ft * 16);
                }
            }
        }
        op += D3 * MUL;
    }
}

extern "C" void kernel_launch(void* const* d_in, const int* in_sizes, int n_in,
                              void* d_out, int out_size, void* d_ws, size_t ws_size,
                              hipStream_t stream) {
    const float* x1 = (const float*)d_in[0];
    const float* x2 = (const float*)d_in[1];
    const float* cg = (const float*)d_in[2];
    float* out = (float*)d_out;

    dim3 grid((BATCH / RPB) * 2);
    dim3 block(256);
    tp_kernel<<<grid, block, FCHUNK * ROWB, stream>>>(x1, x2, cg, out);
}